// Round 10
// baseline (465.229 us; speedup 1.0000x reference)
//
#include <hip/hip_runtime.h>
#include <hip/hip_bf16.h>
#include <math.h>

#define NN   16384
#define EE   524288
#define TOTE (EE + NN)   // edges + self loops
#define CAP  128         // padded CSR row capacity (max deg+1 ~ 65 for this graph)

typedef short s16x8 __attribute__((ext_vector_type(8)));
typedef float f32x16 __attribute__((ext_vector_type(16)));

__device__ inline unsigned short bf16r(float f) {   // fp32 -> bf16 RNE
    unsigned int u = __float_as_uint(f);
    return (unsigned short)((u + 0x7FFFu + ((u >> 16) & 1u)) >> 16);
}

// ---- prep: padded-CSR fill + x->bf16 + weight transposes + BN fold
// cur pre-zeroed by memsetAsync. segments: [0,S0) x | [S0,S1) W1t |
// [S1,S2) W2t | [S2,S3) W3t | [S3,S4) skWt | [S4,S4+256) BN fold
__global__ void k_prep(const float* __restrict__ x,  const float* __restrict__ W1,
                       const float* __restrict__ W2, const float* __restrict__ W3,
                       const float* __restrict__ skW,
                       const float* __restrict__ b1, const float* __restrict__ gamma,
                       const float* __restrict__ beta, const float* __restrict__ mean,
                       const float* __restrict__ var,  const int* __restrict__ ei,
                       unsigned short* __restrict__ xb,  unsigned short* __restrict__ W1t,
                       unsigned short* __restrict__ W2t, unsigned short* __restrict__ W3t,
                       unsigned short* __restrict__ skWt,
                       float* __restrict__ bnA, float* __restrict__ bnC,
                       int* __restrict__ cur, int* __restrict__ cs) {
    const int S0 = NN * 128;
    const int S1 = S0 + 256 * 128;
    const int S2 = S1 + 128 * 256;
    const int S3 = S2 + 64 * 128;
    const int S4 = S3 + 64 * 128;
    int i = blockIdx.x * 256 + threadIdx.x;
    if (i < TOTE) {
        int s, d;
        if (i < EE) { s = ei[i]; d = ei[EE + i]; }
        else        { s = d = i - EE; }            // self loop
        int pos = atomicAdd(&cur[d], 1);
        if (pos < CAP) cs[(d << 7) + pos] = s;
    }
    if (i < S0) { xb[i] = bf16r(x[i]); }
    else if (i < S1) { int j = i - S0; int n = j >> 7, k = j & 127; W1t[j] = bf16r(W1[k * 256 + n]); }
    else if (i < S2) { int j = i - S1; int n = j >> 8, k = j & 255; W2t[j] = bf16r(W2[k * 128 + n]); }
    else if (i < S3) { int j = i - S2; int n = j >> 7, k = j & 127; W3t[j] = (n < 48) ? bf16r(W3[k * 48 + n]) : 0; }
    else if (i < S4) { int j = i - S3; int n = j >> 7, k = j & 127; skWt[j] = (n < 48) ? bf16r(skW[k * 48 + n]) : 0; }
    else if (i < S4 + 256) {
        int j = i - S4;
        float a = gamma[j] * rsqrtf(var[j] + 1e-5f);
        bnA[j] = a;
        bnC[j] = (b1[j] - mean[j]) * a + beta[j];
    }
}

// ------------- dinv = rsqrt(cnt) (cnt includes self loop), xbs = bf16(x*dinv)
__global__ void k_xbs(const float* __restrict__ x, const int* __restrict__ cur,
                      float* __restrict__ dinv, unsigned short* __restrict__ xbs) {
    int i = blockIdx.x * 256 + threadIdx.x;       // NN*128 threads
    if (i < NN) dinv[i] = rsqrtf((float)cur[i]);
    xbs[i] = bf16r(x[i] * rsqrtf((float)cur[i >> 7]));
}

// ===== fused conv1+conv2 pipeline: agg1 -> GEMM1(BN+ReLU) -> GEMM2 =====
// One block (512 thr, 8 waves) per 32-node row-tile; all stages block-local.
__global__ __launch_bounds__(512) void k_enc1(
        const unsigned short* __restrict__ xbs, const int* __restrict__ cur,
        const int* __restrict__ cs, const float* __restrict__ dinv,
        const unsigned short* __restrict__ W1t, const unsigned short* __restrict__ W2t,
        const float* __restrict__ bnA, const float* __restrict__ bnC,
        unsigned short* __restrict__ h2) {
    __shared__ unsigned int   xs[32][68];     // [32][128] bf16, padded rows (272 B)
    __shared__ unsigned short h1s[32][264];   // [32][256] bf16, padded rows (528 B)
    int tid = threadIdx.x;
    int wv = tid >> 6, l = tid & 63;
    int nb0 = blockIdx.x * 32;
    const unsigned int* Hp = (const unsigned int*)xbs;   // [row][64] u32 view

    // ---- P1: aggregation
    for (int it = 0; it < 4; it++) {
        int lr = wv * 4 + it;
        int node = nb0 + lr;
        int cnt = cur[node]; if (cnt > CAP) cnt = CAP;
        int s0 = node << 7;
        float ax = 0.f, ay = 0.f;
        for (int base = 0; base < cnt; base += 64) {
            int nbv = cnt - base; if (nbv > 64) nbv = 64;
            int vi = (l < nbv) ? cs[s0 + base + l] : 0;
            int e = 0;
            for (; e + 8 <= nbv; e += 8) {
                unsigned int u[8];
#pragma unroll
                for (int q = 0; q < 8; q++) {
                    int iq = __shfl(vi, e + q);
                    u[q] = Hp[(size_t)iq * 64 + l];
                }
#pragma unroll
                for (int q = 0; q < 8; q++) {
                    ax += __uint_as_float(u[q] << 16);
                    ay += __uint_as_float(u[q] & 0xffff0000u);
                }
            }
            for (; e < nbv; e++) {
                int iq = __shfl(vi, e);
                unsigned int u0 = Hp[(size_t)iq * 64 + l];
                ax += __uint_as_float(u0 << 16);
                ay += __uint_as_float(u0 & 0xffff0000u);
            }
        }
        float dn = dinv[node];
        ax *= dn; ay *= dn;
        xs[lr][l] = ((unsigned int)bf16r(ay) << 16) | bf16r(ax);
    }
    __syncthreads();

    // ---- P2: GEMM1 (K=128, 256 cols), A from xs, epi BN+ReLU -> h1s (LDS)
    {
        int r = l & 31, hi = l >> 5, tj = wv;
        const s16x8* bp = (const s16x8*)(W1t + (size_t)(tj * 32 + r) * 128 + 8 * hi);
        f32x16 c = {};
#pragma unroll
        for (int kk = 0; kk < 8; kk++) {
            s16x8 a = *(const s16x8*)((const unsigned short*)&xs[r][0] + 16 * kk + 8 * hi);
            c = __builtin_amdgcn_mfma_f32_32x32x16_bf16(a, bp[2 * kk], c, 0, 0, 0);
        }
        int col = tj * 32 + r;
        float A0 = bnA[col], C0 = bnC[col];
#pragma unroll
        for (int reg = 0; reg < 16; reg++) {
            int row = (reg & 3) + 8 * (reg >> 2) + 4 * hi;
            h1s[row][col] = bf16r(fmaxf(c[reg] * A0 + C0, 0.f));
        }
    }
    __syncthreads();

    // ---- P3: GEMM2 (K=256, 128 cols), A from h1s, epi *dinv[row] -> h2 global
    if (wv < 4) {
        int r = l & 31, hi = l >> 5, tj = wv;
        const s16x8* bp = (const s16x8*)(W2t + (size_t)(tj * 32 + r) * 256 + 8 * hi);
        f32x16 c = {};
#pragma unroll
        for (int kk = 0; kk < 16; kk++) {
            s16x8 a = *(const s16x8*)(&h1s[r][16 * kk + 8 * hi]);
            c = __builtin_amdgcn_mfma_f32_32x32x16_bf16(a, bp[2 * kk], c, 0, 0, 0);
        }
        int col = tj * 32 + r;
#pragma unroll
        for (int reg = 0; reg < 16; reg++) {
            int row = (reg & 3) + 8 * (reg >> 2) + 4 * hi;
            int grow = nb0 + row;
            h2[(size_t)grow * 128 + col] = bf16r(c[reg] * dinv[grow]);
        }
    }
}

// ===== fused conv2-agg + conv3-GEMM + skip-GEMM =====
// One block (512 thr, 8 waves) per 32-node tile.
// P1: wave w aggregates nodes {4w..4w+3}: h2a = relu(agg(h2)*dinv + b2) -> LDS
// P2: waves 0-1: h3b = bf16((h2a @ W3t^T)*dinv[row]); waves 2-3: idb = xb@skWt^T+skb
__global__ __launch_bounds__(512) void k_enc2(
        const unsigned short* __restrict__ h2, const int* __restrict__ cur,
        const int* __restrict__ cs, const float* __restrict__ dinv,
        const float* __restrict__ b2, const unsigned short* __restrict__ W3t,
        const unsigned short* __restrict__ xb, const unsigned short* __restrict__ skWt,
        const float* __restrict__ skb,
        unsigned short* __restrict__ h3b, float* __restrict__ idb) {
    __shared__ unsigned int hs[32][68];   // h2a tile, bf16x2 packed, padded (272 B)
    int tid = threadIdx.x;
    int wv = tid >> 6, l = tid & 63;
    int nb0 = blockIdx.x * 32;
    const unsigned int* Hp = (const unsigned int*)h2;   // [row][64] u32 view

    // ---- P1: aggregation with +b2, ReLU epilogue (same math as k_agg128<2>)
    for (int it = 0; it < 4; it++) {
        int lr = wv * 4 + it;
        int node = nb0 + lr;
        int cnt = cur[node]; if (cnt > CAP) cnt = CAP;
        int s0 = node << 7;
        float ax = 0.f, ay = 0.f;
        for (int base = 0; base < cnt; base += 64) {
            int nbv = cnt - base; if (nbv > 64) nbv = 64;
            int vi = (l < nbv) ? cs[s0 + base + l] : 0;
            int e = 0;
            for (; e + 8 <= nbv; e += 8) {
                unsigned int u[8];
#pragma unroll
                for (int q = 0; q < 8; q++) {
                    int iq = __shfl(vi, e + q);
                    u[q] = Hp[(size_t)iq * 64 + l];
                }
#pragma unroll
                for (int q = 0; q < 8; q++) {
                    ax += __uint_as_float(u[q] << 16);
                    ay += __uint_as_float(u[q] & 0xffff0000u);
                }
            }
            for (; e < nbv; e++) {
                int iq = __shfl(vi, e);
                unsigned int u0 = Hp[(size_t)iq * 64 + l];
                ax += __uint_as_float(u0 << 16);
                ay += __uint_as_float(u0 & 0xffff0000u);
            }
        }
        float dn = dinv[node];
        ax = fmaxf(ax * dn + b2[2 * l], 0.f);
        ay = fmaxf(ay * dn + b2[2 * l + 1], 0.f);
        hs[lr][l] = ((unsigned int)bf16r(ay) << 16) | bf16r(ax);
    }
    __syncthreads();

    // ---- P2: two GEMMs (K=128, 64 cols each)
    if (wv < 4) {
        int r = l & 31, hi = l >> 5;
        int tj = wv & 1;
        bool skip = (wv >= 2);
        const s16x8* bp = (const s16x8*)((skip ? skWt : W3t) + (size_t)(tj * 32 + r) * 128 + 8 * hi);
        const s16x8* apg = (const s16x8*)(xb + (size_t)(nb0 + r) * 128 + 8 * hi);
        f32x16 c = {};
#pragma unroll
        for (int kk = 0; kk < 8; kk++) {
            s16x8 a = skip ? apg[2 * kk]
                           : *(const s16x8*)((const unsigned short*)&hs[r][0] + 16 * kk + 8 * hi);
            c = __builtin_amdgcn_mfma_f32_32x32x16_bf16(a, bp[2 * kk], c, 0, 0, 0);
        }
        int col = tj * 32 + r;
        if (!skip) {
#pragma unroll
            for (int reg = 0; reg < 16; reg++) {
                int row = (reg & 3) + 8 * (reg >> 2) + 4 * hi;
                int grow = nb0 + row;
                h3b[(size_t)grow * 64 + col] = bf16r(c[reg] * dinv[grow]);
            }
        } else {
            float add = (col < 48) ? skb[col] : 0.f;
#pragma unroll
            for (int reg = 0; reg < 16; reg++) {
                int row = (reg & 3) + 8 * (reg >> 2) + 4 * hi;
                int grow = nb0 + row;
                idb[(size_t)grow * 64 + col] = c[reg] + add;
            }
        }
    }
}

// --------- final aggregation (pre-scaled bf16 h3, stride 64) + z/bf16/dp
__global__ void k_aggz(const unsigned short* __restrict__ H, const int* __restrict__ cur,
                       const int* __restrict__ cs, const float* __restrict__ dinv,
                       const float* __restrict__ b3, const float* __restrict__ idb,
                       const float* __restrict__ dpW1, const float* __restrict__ dpb1,
                       const float* __restrict__ dpW2, const float* __restrict__ dpb2,
                       float* __restrict__ zout, unsigned short* __restrict__ zb,
                       float* __restrict__ dpout) {
    int node = blockIdx.x * 4 + (threadIdx.x >> 6);
    int lane = threadIdx.x & 63;
    int cnt = cur[node]; if (cnt > CAP) cnt = CAP;
    int s0 = node << 7;
    float a = 0.f;
    for (int base = 0; base < cnt; base += 64) {
        int nb = cnt - base; if (nb > 64) nb = 64;
        int vi = (lane < nb) ? cs[s0 + base + lane] : 0;
        int e = 0;
        for (; e + 8 <= nb; e += 8) {
            float v[8];
#pragma unroll
            for (int q = 0; q < 8; q++) {
                int iq = __shfl(vi, e + q);
                v[q] = __uint_as_float((unsigned int)H[(size_t)iq * 64 + lane] << 16);
            }
#pragma unroll
            for (int q = 0; q < 8; q++) a += v[q];
        }
        for (; e < nb; e++) {
            int iq = __shfl(vi, e);
            a += __uint_as_float((unsigned int)H[(size_t)iq * 64 + lane] << 16);
        }
    }
    float zv = 0.f;
    if (lane < 48) {
        zv = a * dinv[node] + b3[lane] + idb[(size_t)node * 64 + lane];
        zout[(size_t)node * 48 + lane] = zv;
        zb[(size_t)node * 48 + lane] = bf16r(zv);
    }
    // fused degree predictor (all 64 lanes: one hidden unit each)
    float hj = dpb1[lane];
#pragma unroll
    for (int k = 0; k < 48; k++) hj += __shfl(zv, k) * dpW1[k * 64 + lane];
    hj = fmaxf(hj, 0.f);
    float p = hj * dpW2[lane];
    for (int o = 32; o > 0; o >>= 1) p += __shfl_down(p, o);
    if (lane == 0) dpout[node] = p + dpb2[0];
}

// -------------------------------------------- adj = sigmoid(Z Z^T) via MFMA
__global__ __launch_bounds__(256) void k_adj2(const unsigned short* __restrict__ zb,
                                              float* __restrict__ out) {
    int wv = threadIdx.x >> 6;
    int l  = threadIdx.x & 63;
    int ti = blockIdx.y;                  // 0..511
    int tj = blockIdx.x * 4 + wv;         // 0..511
    int r  = l & 31;
    int hi = l >> 5;

    const s16x8* ap = (const s16x8*)(zb + (size_t)(ti * 32 + r) * 48 + 8 * hi);
    const s16x8* bp = (const s16x8*)(zb + (size_t)(tj * 32 + r) * 48 + 8 * hi);

    f32x16 c = {};
#pragma unroll
    for (int kk = 0; kk < 3; kk++) {
        s16x8 a = ap[2 * kk];   // k = 16*kk + 8*hi + 0..7
        s16x8 b = bp[2 * kk];
        c = __builtin_amdgcn_mfma_f32_32x32x16_bf16(a, b, c, 0, 0, 0);
    }

    size_t colbase = (size_t)tj * 32 + r;
#pragma unroll
    for (int reg = 0; reg < 16; reg++) {
        int row = ti * 32 + (reg & 3) + 8 * (reg >> 2) + 4 * hi;
        float v = 1.f / (1.f + __expf(-c[reg]));
        __builtin_nontemporal_store(v, out + (size_t)row * NN + colbase);
    }
}

// ------------------------------------------------------------------ launch
extern "C" void kernel_launch(void* const* d_in, const int* in_sizes, int n_in,
                              void* d_out, int out_size, void* d_ws, size_t ws_size,
                              hipStream_t stream) {
    const float* x      = (const float*)d_in[0];
    const int*   ei     = (const int*)d_in[1];
    const float* W1     = (const float*)d_in[2];
    const float* b1     = (const float*)d_in[3];
    const float* W2     = (const float*)d_in[4];
    const float* b2     = (const float*)d_in[5];
    const float* W3     = (const float*)d_in[6];
    const float* b3     = (const float*)d_in[7];
    const float* skW    = (const float*)d_in[8];
    const float* skb    = (const float*)d_in[9];
    const float* gamma  = (const float*)d_in[10];
    const float* beta   = (const float*)d_in[11];
    const float* mean   = (const float*)d_in[12];
    const float* var    = (const float*)d_in[13];
    const float* dpW1   = (const float*)d_in[14];
    const float* dpb1   = (const float*)d_in[15];
    const float* dpW2   = (const float*)d_in[16];
    const float* dpb2   = (const float*)d_in[17];

    float* zout   = (float*)d_out;                       // [N,48]
    float* adjout = zout + (size_t)NN * 48;              // [N,N]
    float* dpout  = adjout + (size_t)NN * NN;            // [N]

    char* w = (char*)d_ws;
    auto alloc = [&](size_t bytes) {
        char* p = w; w += ((bytes + 255) & ~(size_t)255); return p;
    };
    int*   cur  = (int*)alloc((size_t)NN * 4);
    int*   cs   = (int*)alloc((size_t)NN * CAP * 4);     // padded CSR
    float* dinv = (float*)alloc((size_t)NN * 4);
    float* bnA  = (float*)alloc(256 * 4);
    float* bnC  = (float*)alloc(256 * 4);
    unsigned short* xb   = (unsigned short*)alloc((size_t)NN * 128 * 2);
    unsigned short* xbs  = (unsigned short*)alloc((size_t)NN * 128 * 2);
    unsigned short* W1t  = (unsigned short*)alloc(256 * 128 * 2);
    unsigned short* W2t  = (unsigned short*)alloc(128 * 256 * 2);
    unsigned short* W3t  = (unsigned short*)alloc(64 * 128 * 2);
    unsigned short* skWt = (unsigned short*)alloc(64 * 128 * 2);
    unsigned short* h2   = (unsigned short*)alloc((size_t)NN * 128 * 2);
    unsigned short* h3b  = (unsigned short*)alloc((size_t)NN * 64 * 2);  // pre-scaled
    float* idb  = (float*)alloc((size_t)NN * 64 * 4);   // padded stride 64
    unsigned short* zb = (unsigned short*)alloc((size_t)NN * 48 * 2);

    hipMemsetAsync(cur, 0, (size_t)NN * 4, stream);

    const int PREP = NN * 128 + 256 * 128 + 128 * 256 + 64 * 128 + 64 * 128 + 256;
    k_prep<<<(PREP + 255) / 256, 256, 0, stream>>>(x, W1, W2, W3, skW,
                                                   b1, gamma, beta, mean, var, ei,
                                                   xb, W1t, W2t, W3t, skWt,
                                                   bnA, bnC, cur, cs);
    k_xbs<<<NN * 128 / 256, 256, 0, stream>>>(x, cur, dinv, xbs);

    // conv1 + conv2-GEMM fused: agg1 -> GEMM1(BN+ReLU) -> GEMM2 -> h2
    k_enc1<<<NN / 32, 512, 0, stream>>>(xbs, cur, cs, dinv, W1t, W2t, bnA, bnC, h2);
    // conv2-agg + conv3-GEMM + skip-GEMM fused -> h3b, idb
    k_enc2<<<NN / 32, 512, 0, stream>>>(h2, cur, cs, dinv, b2, W3t, xb, skWt, skb, h3b, idb);
    // final aggregation + z + bf16 + degree predictor
    k_aggz<<<NN / 4, 256, 0, stream>>>(h3b, cur, cs, dinv, b3, idb,
                                       dpW1, dpb1, dpW2, dpb2, zout, zb, dpout);

    // decoder head: adjacency — LAUNCHED TWICE this round (idempotent) to
    // measure adj's true duration via R10-vs-R11 total-time delta.
    k_adj2<<<dim3(128, 512), 256, 0, stream>>>(zb, adjout);
    k_adj2<<<dim3(128, 512), 256, 0, stream>>>(zb, adjout);
}

// Round 11
// 292.333 us; speedup vs baseline: 1.5914x; 1.5914x over previous
//
#include <hip/hip_runtime.h>
#include <hip/hip_bf16.h>
#include <math.h>

#define NN   16384
#define EE   524288
#define TOTE (EE + NN)   // edges + self loops
#define CAP  128         // padded CSR row capacity (max deg+1 ~ 65 for this graph)

typedef short s16x8 __attribute__((ext_vector_type(8)));
typedef float f32x16 __attribute__((ext_vector_type(16)));

__device__ inline unsigned short bf16r(float f) {   // fp32 -> bf16 RNE
    unsigned int u = __float_as_uint(f);
    return (unsigned short)((u + 0x7FFFu + ((u >> 16) & 1u)) >> 16);
}

// ---- prep: padded-CSR fill + x->bf16 + weight transposes + BN fold
__global__ void k_prep(const float* __restrict__ x,  const float* __restrict__ W1,
                       const float* __restrict__ W2, const float* __restrict__ W3,
                       const float* __restrict__ skW,
                       const float* __restrict__ b1, const float* __restrict__ gamma,
                       const float* __restrict__ beta, const float* __restrict__ mean,
                       const float* __restrict__ var,  const int* __restrict__ ei,
                       unsigned short* __restrict__ xb,  unsigned short* __restrict__ W1t,
                       unsigned short* __restrict__ W2t, unsigned short* __restrict__ W3t,
                       unsigned short* __restrict__ skWt,
                       float* __restrict__ bnA, float* __restrict__ bnC,
                       int* __restrict__ cur, int* __restrict__ cs) {
    const int S0 = NN * 128;
    const int S1 = S0 + 256 * 128;
    const int S2 = S1 + 128 * 256;
    const int S3 = S2 + 64 * 128;
    const int S4 = S3 + 64 * 128;
    int i = blockIdx.x * 256 + threadIdx.x;
    if (i < TOTE) {
        int s, d;
        if (i < EE) { s = ei[i]; d = ei[EE + i]; }
        else        { s = d = i - EE; }            // self loop
        int pos = atomicAdd(&cur[d], 1);
        if (pos < CAP) cs[(d << 7) + pos] = s;
    }
    if (i < S0) { xb[i] = bf16r(x[i]); }
    else if (i < S1) { int j = i - S0; int n = j >> 7, k = j & 127; W1t[j] = bf16r(W1[k * 256 + n]); }
    else if (i < S2) { int j = i - S1; int n = j >> 8, k = j & 255; W2t[j] = bf16r(W2[k * 128 + n]); }
    else if (i < S3) { int j = i - S2; int n = j >> 7, k = j & 127; W3t[j] = (n < 48) ? bf16r(W3[k * 48 + n]) : 0; }
    else if (i < S4) { int j = i - S3; int n = j >> 7, k = j & 127; skWt[j] = (n < 48) ? bf16r(skW[k * 48 + n]) : 0; }
    else if (i < S4 + 256) {
        int j = i - S4;
        float a = gamma[j] * rsqrtf(var[j] + 1e-5f);
        bnA[j] = a;
        bnC[j] = (b1[j] - mean[j]) * a + beta[j];
    }
}

// ------------- dinv = rsqrt(cnt) (cnt includes self loop), xbs = bf16(x*dinv)
__global__ void k_xbs(const float* __restrict__ x, const int* __restrict__ cur,
                      float* __restrict__ dinv, unsigned short* __restrict__ xbs) {
    int i = blockIdx.x * 256 + threadIdx.x;       // NN*128 threads
    if (i < NN) dinv[i] = rsqrtf((float)cur[i]);
    xbs[i] = bf16r(x[i] * rsqrtf((float)cur[i >> 7]));
}

// ===== fused conv1+conv2 pipeline: agg1 -> GEMM1(BN+ReLU) -> GEMM2 =====
__global__ __launch_bounds__(512) void k_enc1(
        const unsigned short* __restrict__ xbs, const int* __restrict__ cur,
        const int* __restrict__ cs, const float* __restrict__ dinv,
        const unsigned short* __restrict__ W1t, const unsigned short* __restrict__ W2t,
        const float* __restrict__ bnA, const float* __restrict__ bnC,
        unsigned short* __restrict__ h2) {
    __shared__ unsigned int   xs[32][68];     // [32][128] bf16, padded rows (272 B)
    __shared__ unsigned short h1s[32][264];   // [32][256] bf16, padded rows (528 B)
    int tid = threadIdx.x;
    int wv = tid >> 6, l = tid & 63;
    int nb0 = blockIdx.x * 32;
    const unsigned int* Hp = (const unsigned int*)xbs;   // [row][64] u32 view

    // ---- P1: aggregation
    for (int it = 0; it < 4; it++) {
        int lr = wv * 4 + it;
        int node = nb0 + lr;
        int cnt = cur[node]; if (cnt > CAP) cnt = CAP;
        int s0 = node << 7;
        float ax = 0.f, ay = 0.f;
        for (int base = 0; base < cnt; base += 64) {
            int nbv = cnt - base; if (nbv > 64) nbv = 64;
            int vi = (l < nbv) ? cs[s0 + base + l] : 0;
            int e = 0;
            for (; e + 8 <= nbv; e += 8) {
                unsigned int u[8];
#pragma unroll
                for (int q = 0; q < 8; q++) {
                    int iq = __shfl(vi, e + q);
                    u[q] = Hp[(size_t)iq * 64 + l];
                }
#pragma unroll
                for (int q = 0; q < 8; q++) {
                    ax += __uint_as_float(u[q] << 16);
                    ay += __uint_as_float(u[q] & 0xffff0000u);
                }
            }
            for (; e < nbv; e++) {
                int iq = __shfl(vi, e);
                unsigned int u0 = Hp[(size_t)iq * 64 + l];
                ax += __uint_as_float(u0 << 16);
                ay += __uint_as_float(u0 & 0xffff0000u);
            }
        }
        float dn = dinv[node];
        ax *= dn; ay *= dn;
        xs[lr][l] = ((unsigned int)bf16r(ay) << 16) | bf16r(ax);
    }
    __syncthreads();

    // ---- P2: GEMM1 (K=128, 256 cols), A from xs, epi BN+ReLU -> h1s (LDS)
    {
        int r = l & 31, hi = l >> 5, tj = wv;
        const s16x8* bp = (const s16x8*)(W1t + (size_t)(tj * 32 + r) * 128 + 8 * hi);
        f32x16 c = {};
#pragma unroll
        for (int kk = 0; kk < 8; kk++) {
            s16x8 a = *(const s16x8*)((const unsigned short*)&xs[r][0] + 16 * kk + 8 * hi);
            c = __builtin_amdgcn_mfma_f32_32x32x16_bf16(a, bp[2 * kk], c, 0, 0, 0);
        }
        int col = tj * 32 + r;
        float A0 = bnA[col], C0 = bnC[col];
#pragma unroll
        for (int reg = 0; reg < 16; reg++) {
            int row = (reg & 3) + 8 * (reg >> 2) + 4 * hi;
            h1s[row][col] = bf16r(fmaxf(c[reg] * A0 + C0, 0.f));
        }
    }
    __syncthreads();

    // ---- P3: GEMM2 (K=256, 128 cols), A from h1s, epi *dinv[row] -> h2 global
    if (wv < 4) {
        int r = l & 31, hi = l >> 5, tj = wv;
        const s16x8* bp = (const s16x8*)(W2t + (size_t)(tj * 32 + r) * 256 + 8 * hi);
        f32x16 c = {};
#pragma unroll
        for (int kk = 0; kk < 16; kk++) {
            s16x8 a = *(const s16x8*)(&h1s[r][16 * kk + 8 * hi]);
            c = __builtin_amdgcn_mfma_f32_32x32x16_bf16(a, bp[2 * kk], c, 0, 0, 0);
        }
        int col = tj * 32 + r;
#pragma unroll
        for (int reg = 0; reg < 16; reg++) {
            int row = (reg & 3) + 8 * (reg >> 2) + 4 * hi;
            int grow = nb0 + row;
            h2[(size_t)grow * 128 + col] = bf16r(c[reg] * dinv[grow]);
        }
    }
}

// ===== fused conv2-agg + conv3-GEMM + skip-GEMM =====
__global__ __launch_bounds__(512) void k_enc2(
        const unsigned short* __restrict__ h2, const int* __restrict__ cur,
        const int* __restrict__ cs, const float* __restrict__ dinv,
        const float* __restrict__ b2, const unsigned short* __restrict__ W3t,
        const unsigned short* __restrict__ xb, const unsigned short* __restrict__ skWt,
        const float* __restrict__ skb,
        unsigned short* __restrict__ h3b, float* __restrict__ idb) {
    __shared__ unsigned int hs[32][68];   // h2a tile, bf16x2 packed, padded (272 B)
    int tid = threadIdx.x;
    int wv = tid >> 6, l = tid & 63;
    int nb0 = blockIdx.x * 32;
    const unsigned int* Hp = (const unsigned int*)h2;   // [row][64] u32 view

    // ---- P1: aggregation with +b2, ReLU epilogue
    for (int it = 0; it < 4; it++) {
        int lr = wv * 4 + it;
        int node = nb0 + lr;
        int cnt = cur[node]; if (cnt > CAP) cnt = CAP;
        int s0 = node << 7;
        float ax = 0.f, ay = 0.f;
        for (int base = 0; base < cnt; base += 64) {
            int nbv = cnt - base; if (nbv > 64) nbv = 64;
            int vi = (l < nbv) ? cs[s0 + base + l] : 0;
            int e = 0;
            for (; e + 8 <= nbv; e += 8) {
                unsigned int u[8];
#pragma unroll
                for (int q = 0; q < 8; q++) {
                    int iq = __shfl(vi, e + q);
                    u[q] = Hp[(size_t)iq * 64 + l];
                }
#pragma unroll
                for (int q = 0; q < 8; q++) {
                    ax += __uint_as_float(u[q] << 16);
                    ay += __uint_as_float(u[q] & 0xffff0000u);
                }
            }
            for (; e < nbv; e++) {
                int iq = __shfl(vi, e);
                unsigned int u0 = Hp[(size_t)iq * 64 + l];
                ax += __uint_as_float(u0 << 16);
                ay += __uint_as_float(u0 & 0xffff0000u);
            }
        }
        float dn = dinv[node];
        ax = fmaxf(ax * dn + b2[2 * l], 0.f);
        ay = fmaxf(ay * dn + b2[2 * l + 1], 0.f);
        hs[lr][l] = ((unsigned int)bf16r(ay) << 16) | bf16r(ax);
    }
    __syncthreads();

    // ---- P2: two GEMMs (K=128, 64 cols each)
    if (wv < 4) {
        int r = l & 31, hi = l >> 5;
        int tj = wv & 1;
        bool skip = (wv >= 2);
        const s16x8* bp = (const s16x8*)((skip ? skWt : W3t) + (size_t)(tj * 32 + r) * 128 + 8 * hi);
        const s16x8* apg = (const s16x8*)(xb + (size_t)(nb0 + r) * 128 + 8 * hi);
        f32x16 c = {};
#pragma unroll
        for (int kk = 0; kk < 8; kk++) {
            s16x8 a = skip ? apg[2 * kk]
                           : *(const s16x8*)((const unsigned short*)&hs[r][0] + 16 * kk + 8 * hi);
            c = __builtin_amdgcn_mfma_f32_32x32x16_bf16(a, bp[2 * kk], c, 0, 0, 0);
        }
        int col = tj * 32 + r;
        if (!skip) {
#pragma unroll
            for (int reg = 0; reg < 16; reg++) {
                int row = (reg & 3) + 8 * (reg >> 2) + 4 * hi;
                int grow = nb0 + row;
                h3b[(size_t)grow * 64 + col] = bf16r(c[reg] * dinv[grow]);
            }
        } else {
            float add = (col < 48) ? skb[col] : 0.f;
#pragma unroll
            for (int reg = 0; reg < 16; reg++) {
                int row = (reg & 3) + 8 * (reg >> 2) + 4 * hi;
                int grow = nb0 + row;
                idb[(size_t)grow * 64 + col] = c[reg] + add;
            }
        }
    }
}

// --------- final aggregation (pre-scaled bf16 h3, stride 64) + z/bf16/dp
__global__ void k_aggz(const unsigned short* __restrict__ H, const int* __restrict__ cur,
                       const int* __restrict__ cs, const float* __restrict__ dinv,
                       const float* __restrict__ b3, const float* __restrict__ idb,
                       const float* __restrict__ dpW1, const float* __restrict__ dpb1,
                       const float* __restrict__ dpW2, const float* __restrict__ dpb2,
                       float* __restrict__ zout, unsigned short* __restrict__ zb,
                       float* __restrict__ dpout) {
    int node = blockIdx.x * 4 + (threadIdx.x >> 6);
    int lane = threadIdx.x & 63;
    int cnt = cur[node]; if (cnt > CAP) cnt = CAP;
    int s0 = node << 7;
    float a = 0.f;
    for (int base = 0; base < cnt; base += 64) {
        int nb = cnt - base; if (nb > 64) nb = 64;
        int vi = (lane < nb) ? cs[s0 + base + lane] : 0;
        int e = 0;
        for (; e + 8 <= nb; e += 8) {
            float v[8];
#pragma unroll
            for (int q = 0; q < 8; q++) {
                int iq = __shfl(vi, e + q);
                v[q] = __uint_as_float((unsigned int)H[(size_t)iq * 64 + lane] << 16);
            }
#pragma unroll
            for (int q = 0; q < 8; q++) a += v[q];
        }
        for (; e < nb; e++) {
            int iq = __shfl(vi, e);
            a += __uint_as_float((unsigned int)H[(size_t)iq * 64 + lane] << 16);
        }
    }
    float zv = 0.f;
    if (lane < 48) {
        zv = a * dinv[node] + b3[lane] + idb[(size_t)node * 64 + lane];
        zout[(size_t)node * 48 + lane] = zv;
        zb[(size_t)node * 48 + lane] = bf16r(zv);
    }
    // fused degree predictor (all 64 lanes: one hidden unit each)
    float hj = dpb1[lane];
#pragma unroll
    for (int k = 0; k < 48; k++) hj += __shfl(zv, k) * dpW1[k * 64 + lane];
    hj = fmaxf(hj, 0.f);
    float p = hj * dpW2[lane];
    for (int o = 32; o > 0; o >>= 1) p += __shfl_down(p, o);
    if (lane == 0) dpout[node] = p + dpb2[0];
}

// -------------------- adj = sigmoid(Z Z^T) via MFMA, LDS-repacked stores
// Block (256 thr, 4 waves) computes 32 rows x 128 cols. Per-wave 32x32 MFMA
// tile -> sigmoid -> LDS sm[32][128] f32 -> barrier -> 256 threads store
// 4x float4 each: every instruction = 2 rows x 512 B CONTIGUOUS segments
// (fill-like pattern), plain dwordx4 (no NT). Values byte-identical to R10.
__global__ __launch_bounds__(256) void k_adj2(const unsigned short* __restrict__ zb,
                                              float* __restrict__ out) {
    __shared__ float sm[32][128];
    int wv = threadIdx.x >> 6;
    int l  = threadIdx.x & 63;
    int ti = blockIdx.y;                  // 0..511 (row tile)
    int tj = blockIdx.x * 4 + wv;         // 0..511 (col tile)
    int r  = l & 31;
    int hi = l >> 5;

    const s16x8* ap = (const s16x8*)(zb + (size_t)(ti * 32 + r) * 48 + 8 * hi);
    const s16x8* bp = (const s16x8*)(zb + (size_t)(tj * 32 + r) * 48 + 8 * hi);

    f32x16 c = {};
#pragma unroll
    for (int kk = 0; kk < 3; kk++) {
        s16x8 a = ap[2 * kk];   // k = 16*kk + 8*hi + 0..7
        s16x8 b = bp[2 * kk];
        c = __builtin_amdgcn_mfma_f32_32x32x16_bf16(a, b, c, 0, 0, 0);
    }

    int cbase = wv * 32 + r;
#pragma unroll
    for (int reg = 0; reg < 16; reg++) {
        int row = (reg & 3) + 8 * (reg >> 2) + 4 * hi;
        sm[row][cbase] = 1.f / (1.f + __expf(-c[reg]));
    }
    __syncthreads();

    size_t colb = (size_t)blockIdx.x * 128;
#pragma unroll
    for (int k = 0; k < 4; k++) {
        int fidx = threadIdx.x + 256 * k;
        int row = fidx >> 5, c4 = fidx & 31;
        float4 v = *(const float4*)&sm[row][c4 * 4];
        *(float4*)(out + (size_t)(ti * 32 + row) * NN + colb + c4 * 4) = v;
    }
}

// ------------------------------------------------------------------ launch
extern "C" void kernel_launch(void* const* d_in, const int* in_sizes, int n_in,
                              void* d_out, int out_size, void* d_ws, size_t ws_size,
                              hipStream_t stream) {
    const float* x      = (const float*)d_in[0];
    const int*   ei     = (const int*)d_in[1];
    const float* W1     = (const float*)d_in[2];
    const float* b1     = (const float*)d_in[3];
    const float* W2     = (const float*)d_in[4];
    const float* b2     = (const float*)d_in[5];
    const float* W3     = (const float*)d_in[6];
    const float* b3     = (const float*)d_in[7];
    const float* skW    = (const float*)d_in[8];
    const float* skb    = (const float*)d_in[9];
    const float* gamma  = (const float*)d_in[10];
    const float* beta   = (const float*)d_in[11];
    const float* mean   = (const float*)d_in[12];
    const float* var    = (const float*)d_in[13];
    const float* dpW1   = (const float*)d_in[14];
    const float* dpb1   = (const float*)d_in[15];
    const float* dpW2   = (const float*)d_in[16];
    const float* dpb2   = (const float*)d_in[17];

    float* zout   = (float*)d_out;                       // [N,48]
    float* adjout = zout + (size_t)NN * 48;              // [N,N]
    float* dpout  = adjout + (size_t)NN * NN;            // [N]

    char* w = (char*)d_ws;
    auto alloc = [&](size_t bytes) {
        char* p = w; w += ((bytes + 255) & ~(size_t)255); return p;
    };
    int*   cur  = (int*)alloc((size_t)NN * 4);
    int*   cs   = (int*)alloc((size_t)NN * CAP * 4);     // padded CSR
    float* dinv = (float*)alloc((size_t)NN * 4);
    float* bnA  = (float*)alloc(256 * 4);
    float* bnC  = (float*)alloc(256 * 4);
    unsigned short* xb   = (unsigned short*)alloc((size_t)NN * 128 * 2);
    unsigned short* xbs  = (unsigned short*)alloc((size_t)NN * 128 * 2);
    unsigned short* W1t  = (unsigned short*)alloc(256 * 128 * 2);
    unsigned short* W2t  = (unsigned short*)alloc(128 * 256 * 2);
    unsigned short* W3t  = (unsigned short*)alloc(64 * 128 * 2);
    unsigned short* skWt = (unsigned short*)alloc(64 * 128 * 2);
    unsigned short* h2   = (unsigned short*)alloc((size_t)NN * 128 * 2);
    unsigned short* h3b  = (unsigned short*)alloc((size_t)NN * 64 * 2);  // pre-scaled
    float* idb  = (float*)alloc((size_t)NN * 64 * 4);   // padded stride 64
    unsigned short* zb = (unsigned short*)alloc((size_t)NN * 48 * 2);

    hipMemsetAsync(cur, 0, (size_t)NN * 4, stream);

    const int PREP = NN * 128 + 256 * 128 + 128 * 256 + 64 * 128 + 64 * 128 + 256;
    k_prep<<<(PREP + 255) / 256, 256, 0, stream>>>(x, W1, W2, W3, skW,
                                                   b1, gamma, beta, mean, var, ei,
                                                   xb, W1t, W2t, W3t, skWt,
                                                   bnA, bnC, cur, cs);
    k_xbs<<<NN * 128 / 256, 256, 0, stream>>>(x, cur, dinv, xbs);

    // conv1 + conv2-GEMM fused: agg1 -> GEMM1(BN+ReLU) -> GEMM2 -> h2
    k_enc1<<<NN / 32, 512, 0, stream>>>(xbs, cur, cs, dinv, W1t, W2t, bnA, bnC, h2);
    // conv2-agg + conv3-GEMM + skip-GEMM fused -> h3b, idb
    k_enc2<<<NN / 32, 512, 0, stream>>>(h2, cur, cs, dinv, b2, W3t, xb, skWt, skb, h3b, idb);
    // final aggregation + z + bf16 + degree predictor
    k_aggz<<<NN / 4, 256, 0, stream>>>(h3b, cur, cs, dinv, b3, idb,
                                       dpW1, dpb1, dpW2, dpb2, zout, zb, dpout);

    // decoder head: adjacency (LDS-repacked contiguous stores)
    k_adj2<<<dim3(128, 512), 256, 0, stream>>>(zb, adjout);
}

// Round 12
// 284.297 us; speedup vs baseline: 1.6364x; 1.0283x over previous
//
#include <hip/hip_runtime.h>
#include <hip/hip_bf16.h>
#include <math.h>

#define NN   16384
#define EE   524288
#define TOTE (EE + NN)   // edges + self loops
#define CAP  128         // padded CSR row capacity (max deg+1 ~ 65 for this graph)

typedef short s16x8 __attribute__((ext_vector_type(8)));
typedef float f32x16 __attribute__((ext_vector_type(16)));

__device__ inline unsigned short bf16r(float f) {   // fp32 -> bf16 RNE
    unsigned int u = __float_as_uint(f);
    return (unsigned short)((u + 0x7FFFu + ((u >> 16) & 1u)) >> 16);
}

// ---- prep: padded-CSR fill + x->bf16 + weight transposes + BN fold
__global__ void k_prep(const float* __restrict__ x,  const float* __restrict__ W1,
                       const float* __restrict__ W2, const float* __restrict__ W3,
                       const float* __restrict__ skW,
                       const float* __restrict__ b1, const float* __restrict__ gamma,
                       const float* __restrict__ beta, const float* __restrict__ mean,
                       const float* __restrict__ var,  const int* __restrict__ ei,
                       unsigned short* __restrict__ xb,  unsigned short* __restrict__ W1t,
                       unsigned short* __restrict__ W2t, unsigned short* __restrict__ W3t,
                       unsigned short* __restrict__ skWt,
                       float* __restrict__ bnA, float* __restrict__ bnC,
                       int* __restrict__ cur, int* __restrict__ cs) {
    const int S0 = NN * 128;
    const int S1 = S0 + 256 * 128;
    const int S2 = S1 + 128 * 256;
    const int S3 = S2 + 64 * 128;
    const int S4 = S3 + 64 * 128;
    int i = blockIdx.x * 256 + threadIdx.x;
    if (i < TOTE) {
        int s, d;
        if (i < EE) { s = ei[i]; d = ei[EE + i]; }
        else        { s = d = i - EE; }            // self loop
        int pos = atomicAdd(&cur[d], 1);
        if (pos < CAP) cs[(d << 7) + pos] = s;
    }
    if (i < S0) { xb[i] = bf16r(x[i]); }
    else if (i < S1) { int j = i - S0; int n = j >> 7, k = j & 127; W1t[j] = bf16r(W1[k * 256 + n]); }
    else if (i < S2) { int j = i - S1; int n = j >> 8, k = j & 255; W2t[j] = bf16r(W2[k * 128 + n]); }
    else if (i < S3) { int j = i - S2; int n = j >> 7, k = j & 127; W3t[j] = (n < 48) ? bf16r(W3[k * 48 + n]) : 0; }
    else if (i < S4) { int j = i - S3; int n = j >> 7, k = j & 127; skWt[j] = (n < 48) ? bf16r(skW[k * 48 + n]) : 0; }
    else if (i < S4 + 256) {
        int j = i - S4;
        float a = gamma[j] * rsqrtf(var[j] + 1e-5f);
        bnA[j] = a;
        bnC[j] = (b1[j] - mean[j]) * a + beta[j];
    }
}

// ------------- dinv = rsqrt(cnt) (cnt includes self loop), xbs = bf16(x*dinv)
__global__ void k_xbs(const float* __restrict__ x, const int* __restrict__ cur,
                      float* __restrict__ dinv, unsigned short* __restrict__ xbs) {
    int i = blockIdx.x * 256 + threadIdx.x;       // NN*128 threads
    if (i < NN) dinv[i] = rsqrtf((float)cur[i]);
    xbs[i] = bf16r(x[i] * rsqrtf((float)cur[i >> 7]));
}

// ===== fused conv1+conv2 pipeline: agg1 -> GEMM1(BN+ReLU) -> GEMM2 =====
__global__ __launch_bounds__(512) void k_enc1(
        const unsigned short* __restrict__ xbs, const int* __restrict__ cur,
        const int* __restrict__ cs, const float* __restrict__ dinv,
        const unsigned short* __restrict__ W1t, const unsigned short* __restrict__ W2t,
        const float* __restrict__ bnA, const float* __restrict__ bnC,
        unsigned short* __restrict__ h2) {
    __shared__ unsigned int   xs[32][68];     // [32][128] bf16, padded rows (272 B)
    __shared__ unsigned short h1s[32][264];   // [32][256] bf16, padded rows (528 B)
    int tid = threadIdx.x;
    int wv = tid >> 6, l = tid & 63;
    int nb0 = blockIdx.x * 32;
    const unsigned int* Hp = (const unsigned int*)xbs;   // [row][64] u32 view

    // ---- P1: aggregation
    for (int it = 0; it < 4; it++) {
        int lr = wv * 4 + it;
        int node = nb0 + lr;
        int cnt = cur[node]; if (cnt > CAP) cnt = CAP;
        int s0 = node << 7;
        float ax = 0.f, ay = 0.f;
        for (int base = 0; base < cnt; base += 64) {
            int nbv = cnt - base; if (nbv > 64) nbv = 64;
            int vi = (l < nbv) ? cs[s0 + base + l] : 0;
            int e = 0;
            for (; e + 8 <= nbv; e += 8) {
                unsigned int u[8];
#pragma unroll
                for (int q = 0; q < 8; q++) {
                    int iq = __shfl(vi, e + q);
                    u[q] = Hp[(size_t)iq * 64 + l];
                }
#pragma unroll
                for (int q = 0; q < 8; q++) {
                    ax += __uint_as_float(u[q] << 16);
                    ay += __uint_as_float(u[q] & 0xffff0000u);
                }
            }
            for (; e < nbv; e++) {
                int iq = __shfl(vi, e);
                unsigned int u0 = Hp[(size_t)iq * 64 + l];
                ax += __uint_as_float(u0 << 16);
                ay += __uint_as_float(u0 & 0xffff0000u);
            }
        }
        float dn = dinv[node];
        ax *= dn; ay *= dn;
        xs[lr][l] = ((unsigned int)bf16r(ay) << 16) | bf16r(ax);
    }
    __syncthreads();

    // ---- P2: GEMM1 (K=128, 256 cols), A from xs, epi BN+ReLU -> h1s (LDS)
    {
        int r = l & 31, hi = l >> 5, tj = wv;
        const s16x8* bp = (const s16x8*)(W1t + (size_t)(tj * 32 + r) * 128 + 8 * hi);
        f32x16 c = {};
#pragma unroll
        for (int kk = 0; kk < 8; kk++) {
            s16x8 a = *(const s16x8*)((const unsigned short*)&xs[r][0] + 16 * kk + 8 * hi);
            c = __builtin_amdgcn_mfma_f32_32x32x16_bf16(a, bp[2 * kk], c, 0, 0, 0);
        }
        int col = tj * 32 + r;
        float A0 = bnA[col], C0 = bnC[col];
#pragma unroll
        for (int reg = 0; reg < 16; reg++) {
            int row = (reg & 3) + 8 * (reg >> 2) + 4 * hi;
            h1s[row][col] = bf16r(fmaxf(c[reg] * A0 + C0, 0.f));
        }
    }
    __syncthreads();

    // ---- P3: GEMM2 (K=256, 128 cols), A from h1s, epi *dinv[row] -> h2 global
    if (wv < 4) {
        int r = l & 31, hi = l >> 5, tj = wv;
        const s16x8* bp = (const s16x8*)(W2t + (size_t)(tj * 32 + r) * 256 + 8 * hi);
        f32x16 c = {};
#pragma unroll
        for (int kk = 0; kk < 16; kk++) {
            s16x8 a = *(const s16x8*)(&h1s[r][16 * kk + 8 * hi]);
            c = __builtin_amdgcn_mfma_f32_32x32x16_bf16(a, bp[2 * kk], c, 0, 0, 0);
        }
        int col = tj * 32 + r;
#pragma unroll
        for (int reg = 0; reg < 16; reg++) {
            int row = (reg & 3) + 8 * (reg >> 2) + 4 * hi;
            int grow = nb0 + row;
            h2[(size_t)grow * 128 + col] = bf16r(c[reg] * dinv[grow]);
        }
    }
}

// ===== fused conv2-agg + conv3-GEMM + skip-GEMM =====
__global__ __launch_bounds__(512) void k_enc2(
        const unsigned short* __restrict__ h2, const int* __restrict__ cur,
        const int* __restrict__ cs, const float* __restrict__ dinv,
        const float* __restrict__ b2, const unsigned short* __restrict__ W3t,
        const unsigned short* __restrict__ xb, const unsigned short* __restrict__ skWt,
        const float* __restrict__ skb,
        unsigned short* __restrict__ h3b, float* __restrict__ idb) {
    __shared__ unsigned int hs[32][68];   // h2a tile, bf16x2 packed, padded (272 B)
    int tid = threadIdx.x;
    int wv = tid >> 6, l = tid & 63;
    int nb0 = blockIdx.x * 32;
    const unsigned int* Hp = (const unsigned int*)h2;   // [row][64] u32 view

    // ---- P1: aggregation with +b2, ReLU epilogue
    for (int it = 0; it < 4; it++) {
        int lr = wv * 4 + it;
        int node = nb0 + lr;
        int cnt = cur[node]; if (cnt > CAP) cnt = CAP;
        int s0 = node << 7;
        float ax = 0.f, ay = 0.f;
        for (int base = 0; base < cnt; base += 64) {
            int nbv = cnt - base; if (nbv > 64) nbv = 64;
            int vi = (l < nbv) ? cs[s0 + base + l] : 0;
            int e = 0;
            for (; e + 8 <= nbv; e += 8) {
                unsigned int u[8];
#pragma unroll
                for (int q = 0; q < 8; q++) {
                    int iq = __shfl(vi, e + q);
                    u[q] = Hp[(size_t)iq * 64 + l];
                }
#pragma unroll
                for (int q = 0; q < 8; q++) {
                    ax += __uint_as_float(u[q] << 16);
                    ay += __uint_as_float(u[q] & 0xffff0000u);
                }
            }
            for (; e < nbv; e++) {
                int iq = __shfl(vi, e);
                unsigned int u0 = Hp[(size_t)iq * 64 + l];
                ax += __uint_as_float(u0 << 16);
                ay += __uint_as_float(u0 & 0xffff0000u);
            }
        }
        float dn = dinv[node];
        ax = fmaxf(ax * dn + b2[2 * l], 0.f);
        ay = fmaxf(ay * dn + b2[2 * l + 1], 0.f);
        hs[lr][l] = ((unsigned int)bf16r(ay) << 16) | bf16r(ax);
    }
    __syncthreads();

    // ---- P2: two GEMMs (K=128, 64 cols each)
    if (wv < 4) {
        int r = l & 31, hi = l >> 5;
        int tj = wv & 1;
        bool skip = (wv >= 2);
        const s16x8* bp = (const s16x8*)((skip ? skWt : W3t) + (size_t)(tj * 32 + r) * 128 + 8 * hi);
        const s16x8* apg = (const s16x8*)(xb + (size_t)(nb0 + r) * 128 + 8 * hi);
        f32x16 c = {};
#pragma unroll
        for (int kk = 0; kk < 8; kk++) {
            s16x8 a = skip ? apg[2 * kk]
                           : *(const s16x8*)((const unsigned short*)&hs[r][0] + 16 * kk + 8 * hi);
            c = __builtin_amdgcn_mfma_f32_32x32x16_bf16(a, bp[2 * kk], c, 0, 0, 0);
        }
        int col = tj * 32 + r;
        if (!skip) {
#pragma unroll
            for (int reg = 0; reg < 16; reg++) {
                int row = (reg & 3) + 8 * (reg >> 2) + 4 * hi;
                int grow = nb0 + row;
                h3b[(size_t)grow * 64 + col] = bf16r(c[reg] * dinv[grow]);
            }
        } else {
            float add = (col < 48) ? skb[col] : 0.f;
#pragma unroll
            for (int reg = 0; reg < 16; reg++) {
                int row = (reg & 3) + 8 * (reg >> 2) + 4 * hi;
                int grow = nb0 + row;
                idb[(size_t)grow * 64 + col] = c[reg] + add;
            }
        }
    }
}

// --------- final aggregation (pre-scaled bf16 h3, stride 64) + z/bf16/dp
__global__ void k_aggz(const unsigned short* __restrict__ H, const int* __restrict__ cur,
                       const int* __restrict__ cs, const float* __restrict__ dinv,
                       const float* __restrict__ b3, const float* __restrict__ idb,
                       const float* __restrict__ dpW1, const float* __restrict__ dpb1,
                       const float* __restrict__ dpW2, const float* __restrict__ dpb2,
                       float* __restrict__ zout, unsigned short* __restrict__ zb,
                       float* __restrict__ dpout) {
    int node = blockIdx.x * 4 + (threadIdx.x >> 6);
    int lane = threadIdx.x & 63;
    int cnt = cur[node]; if (cnt > CAP) cnt = CAP;
    int s0 = node << 7;
    float a = 0.f;
    for (int base = 0; base < cnt; base += 64) {
        int nb = cnt - base; if (nb > 64) nb = 64;
        int vi = (lane < nb) ? cs[s0 + base + lane] : 0;
        int e = 0;
        for (; e + 8 <= nb; e += 8) {
            float v[8];
#pragma unroll
            for (int q = 0; q < 8; q++) {
                int iq = __shfl(vi, e + q);
                v[q] = __uint_as_float((unsigned int)H[(size_t)iq * 64 + lane] << 16);
            }
#pragma unroll
            for (int q = 0; q < 8; q++) a += v[q];
        }
        for (; e < nb; e++) {
            int iq = __shfl(vi, e);
            a += __uint_as_float((unsigned int)H[(size_t)iq * 64 + lane] << 16);
        }
    }
    float zv = 0.f;
    if (lane < 48) {
        zv = a * dinv[node] + b3[lane] + idb[(size_t)node * 64 + lane];
        zout[(size_t)node * 48 + lane] = zv;
        zb[(size_t)node * 48 + lane] = bf16r(zv);
    }
    // fused degree predictor (all 64 lanes: one hidden unit each)
    float hj = dpb1[lane];
#pragma unroll
    for (int k = 0; k < 48; k++) hj += __shfl(zv, k) * dpW1[k * 64 + lane];
    hj = fmaxf(hj, 0.f);
    float p = hj * dpW2[lane];
    for (int o = 32; o > 0; o >>= 1) p += __shfl_down(p, o);
    if (lane == 0) dpout[node] = p + dpb2[0];
}

// -------------------- adj = sigmoid(Z Z^T) via MFMA (R10 NT-store version)
__global__ __launch_bounds__(256) void k_adj2(const unsigned short* __restrict__ zb,
                                              float* __restrict__ out) {
    int wv = threadIdx.x >> 6;
    int l  = threadIdx.x & 63;
    int ti = blockIdx.y;                  // 0..511
    int tj = blockIdx.x * 4 + wv;         // 0..511
    int r  = l & 31;
    int hi = l >> 5;

    const s16x8* ap = (const s16x8*)(zb + (size_t)(ti * 32 + r) * 48 + 8 * hi);
    const s16x8* bp = (const s16x8*)(zb + (size_t)(tj * 32 + r) * 48 + 8 * hi);

    f32x16 c = {};
#pragma unroll
    for (int kk = 0; kk < 3; kk++) {
        s16x8 a = ap[2 * kk];   // k = 16*kk + 8*hi + 0..7
        s16x8 b = bp[2 * kk];
        c = __builtin_amdgcn_mfma_f32_32x32x16_bf16(a, b, c, 0, 0, 0);
    }

    size_t colbase = (size_t)tj * 32 + r;
#pragma unroll
    for (int reg = 0; reg < 16; reg++) {
        int row = ti * 32 + (reg & 3) + 8 * (reg >> 2) + 4 * hi;
        float v = 1.f / (1.f + __expf(-c[reg]));
        __builtin_nontemporal_store(v, out + (size_t)row * NN + colbase);
    }
}

// ------------------------------------------------------------------ launch
extern "C" void kernel_launch(void* const* d_in, const int* in_sizes, int n_in,
                              void* d_out, int out_size, void* d_ws, size_t ws_size,
                              hipStream_t stream) {
    const float* x      = (const float*)d_in[0];
    const int*   ei     = (const int*)d_in[1];
    const float* W1     = (const float*)d_in[2];
    const float* b1     = (const float*)d_in[3];
    const float* W2     = (const float*)d_in[4];
    const float* b2     = (const float*)d_in[5];
    const float* W3     = (const float*)d_in[6];
    const float* b3     = (const float*)d_in[7];
    const float* skW    = (const float*)d_in[8];
    const float* skb    = (const float*)d_in[9];
    const float* gamma  = (const float*)d_in[10];
    const float* beta   = (const float*)d_in[11];
    const float* mean   = (const float*)d_in[12];
    const float* var    = (const float*)d_in[13];
    const float* dpW1   = (const float*)d_in[14];
    const float* dpb1   = (const float*)d_in[15];
    const float* dpW2   = (const float*)d_in[16];
    const float* dpb2   = (const float*)d_in[17];

    float* zout   = (float*)d_out;                       // [N,48]
    float* adjout = zout + (size_t)NN * 48;              // [N,N]
    float* dpout  = adjout + (size_t)NN * NN;            // [N]

    char* w = (char*)d_ws;
    auto alloc = [&](size_t bytes) {
        char* p = w; w += ((bytes + 255) & ~(size_t)255); return p;
    };
    int*   cur  = (int*)alloc((size_t)NN * 4);
    int*   cs   = (int*)alloc((size_t)NN * CAP * 4);     // padded CSR
    float* dinv = (float*)alloc((size_t)NN * 4);
    float* bnA  = (float*)alloc(256 * 4);
    float* bnC  = (float*)alloc(256 * 4);
    unsigned short* xb   = (unsigned short*)alloc((size_t)NN * 128 * 2);
    unsigned short* xbs  = (unsigned short*)alloc((size_t)NN * 128 * 2);
    unsigned short* W1t  = (unsigned short*)alloc(256 * 128 * 2);
    unsigned short* W2t  = (unsigned short*)alloc(128 * 256 * 2);
    unsigned short* W3t  = (unsigned short*)alloc(64 * 128 * 2);
    unsigned short* skWt = (unsigned short*)alloc(64 * 128 * 2);
    unsigned short* h2   = (unsigned short*)alloc((size_t)NN * 128 * 2);
    unsigned short* h3b  = (unsigned short*)alloc((size_t)NN * 64 * 2);  // pre-scaled
    float* idb  = (float*)alloc((size_t)NN * 64 * 4);   // padded stride 64
    unsigned short* zb = (unsigned short*)alloc((size_t)NN * 48 * 2);

    hipMemsetAsync(cur, 0, (size_t)NN * 4, stream);

    const int PREP = NN * 128 + 256 * 128 + 128 * 256 + 64 * 128 + 64 * 128 + 256;
    k_prep<<<(PREP + 255) / 256, 256, 0, stream>>>(x, W1, W2, W3, skW,
                                                   b1, gamma, beta, mean, var, ei,
                                                   xb, W1t, W2t, W3t, skWt,
                                                   bnA, bnC, cur, cs);
    k_xbs<<<NN * 128 / 256, 256, 0, stream>>>(x, cur, dinv, xbs);

    // conv1 + conv2-GEMM fused: agg1 -> GEMM1(BN+ReLU) -> GEMM2 -> h2
    k_enc1<<<NN / 32, 512, 0, stream>>>(xbs, cur, cs, dinv, W1t, W2t, bnA, bnC, h2);
    // conv2-agg + conv3-GEMM + skip-GEMM fused -> h3b, idb
    k_enc2<<<NN / 32, 512, 0, stream>>>(h2, cur, cs, dinv, b2, W3t, xb, skWt, skb, h3b, idb);
    // final aggregation + z + bf16 + degree predictor
    k_aggz<<<NN / 4, 256, 0, stream>>>(h3b, cur, cs, dinv, b3, idb,
                                       dpW1, dpb1, dpW2, dpb2, zout, zb, dpout);

    // decoder head: adjacency (direct NT stores — measured-best path)
    k_adj2<<<dim3(128, 512), 256, 0, stream>>>(zb, adjout);
}